// Round 15
// baseline (169.248 us; speedup 1.0000x reference)
//
#include <hip/hip_runtime.h>

// B=2, S=32, C=256, L=640, H=5, D=128.  M = B*S*C = 16384, L = 640 = H*D.
//
// ws layout (bytes):
//   XPK  @ 0    : x packed in MFMA A-frag order [1024 mt][20 kb][64 lane][8]
//                 (reused after qkv as ATP = attn output, ALSO packed)
//   QB   @ SZ   : q bf16 [16384][640];  KB @ 2SZ;  VTB @ 3SZ (v transposed)
//   WPK  @ 4SZ  : Wq|Wk|Wv packed frag-order [120 nt][20 kb][64][8]
//   WPPK        : Wp packed frag-order [40 nt][20 kb][64][8]
//   BPB  bp bf16 [640];  FLAG u32 (1 = inputs fp32)

typedef unsigned short u16;
typedef __bf16 bf16x8 __attribute__((ext_vector_type(8)));
typedef float f32x4 __attribute__((ext_vector_type(4)));

__device__ __forceinline__ u16 f2bf(float f){
  union { float f; unsigned u; } v; v.f = f;
  unsigned r = v.u + 0x7fffu + ((v.u >> 16) & 1u);
  return (u16)(r >> 16);
}
__device__ __forceinline__ float bf2f(u16 u){
  union { unsigned u; float f; } v; v.u = ((unsigned)u) << 16;
  return v.f;
}

// ---- attention LDS swizzles (verified r1-r14) ----
__device__ __forceinline__ int k_off (int e, int d){ return e*256 + (((d>>3) ^ (e&7)))*16 + (d&7)*2; }
__device__ __forceinline__ int vt_off(int d, int e){ return d*512 + (((e>>3) ^ (d&7)))*16 + (e&7)*2; }
__device__ __forceinline__ int p_off2(int c, int el){ return c*128 + (((el>>3) ^ (c&7)))*16 + (el&7)*2; }

// ------------------------------------------------------------------
// Fused dtype-detect + convert + repack of x and all weights into MFMA
// fragment order (r14 verbatim).
__global__ __launch_bounds__(256) void k_convert_all(
    const void* __restrict__ xsrc, const void* __restrict__ s1, const void* __restrict__ s2,
    const void* __restrict__ s3, const void* __restrict__ s4, const void* __restrict__ s5,
    u16* __restrict__ xpk, u16* __restrict__ wpk, u16* __restrict__ wppk,
    u16* __restrict__ bpb, unsigned* __restrict__ flagOut){
  __shared__ unsigned sflag;
  const int tid = threadIdx.x;
  const u16* xs = (const u16*)xsrc;
  if (tid < 64){
    int cnt = 0;
    for (int i = tid; i < 1024; i += 64){
      unsigned e = (xs[2*i] >> 7) & 0xffu;
      cnt += (e >= 143u) ? 1 : 0;
    }
    #pragma unroll
    for (int m = 1; m < 64; m <<= 1) cnt += __shfl_xor(cnt, m);
    if (tid == 0) sflag = (cnt > 16) ? 1u : 0u;
  }
  __syncthreads();
  const unsigned flag = sflag;
  if (blockIdx.x == 0 && tid == 0) *flagOut = flag;

  #pragma unroll
  for (int it = 0; it < 4; ++it){
    size_t i = (size_t)blockIdx.x*1024 + it*256 + tid;
    if (i >= 3031200) break;
    const void* src; size_t off; u16* dp;
    if (i < 2621440){
      int e0 = ((int)i & 1) * 4;
      int grp = (int)(i >> 1);
      int lane = grp & 63;
      int t = grp >> 6;
      int kb = t % 20, mt = t / 20;
      int row = mt*16 + (lane & 15);
      int col = kb*32 + ((lane >> 4) & 3)*8 + e0;
      src = xsrc; off = ((size_t)row*640 + col) >> 2; dp = xpk + i*4;
    } else {
      size_t j = i - 2621440;
      if (j < 409600){
        int iswp = (j >= 307200);
        int j2 = iswp ? (int)(j - 307200) : (int)j;
        int P = j2 * 4;
        int eo = P & 7;
        int grp = P >> 3;
        int lo = grp & 15, g = (grp >> 4) & 3;
        int t2 = grp >> 6;
        int kb = t2 % 20, nt = t2 / 20;
        int n = nt*16 + lo;
        int k = kb*32 + g*8 + eo;
        if (iswp){
          src = s4; off = (size_t)n*160 + (k >> 2); dp = wppk + (size_t)j2*4;
        } else {
          int seg = n / 640, r = n % 640;
          src = (seg==0) ? s1 : (seg==1) ? s2 : s3;
          off = (size_t)r*160 + (k >> 2); dp = wpk + (size_t)j2*4;
        }
      } else { off = j - 409600; src = s5; dp = bpb + off*4; }
    }
    if (flag){
      float4 v = ((const float4*)src)[off];
      ushort4 o;
      o.x = f2bf(v.x); o.y = f2bf(v.y); o.z = f2bf(v.z); o.w = f2bf(v.w);
      *(ushort4*)dp = o;
    } else {
      *(ushort4*)dp = ((const ushort4*)src)[off];
    }
  }
}

// ------------------------------------------------------------------
// NO-LDS, NO-BARRIER big-tile GEMM.  Per-wave 128x64 output (acc[8][4]),
// block = 256x128 (2x2 waves) -> operand traffic HALVED vs r14 (the
// measured 13.5 TB/s delivery ceiling was the wall).  Ping-pong frag
// buffers (static indexing), manual 2x unroll, 12 loads + 32 MFMA per
// K-step.  MODE 0: A=XPK, B=WPK, qkv scatter epilogue (r10 verbatim).
// MODE 1: A=ATP (packed attn out), B=WPPK, +bias, f32/bf16 per flag.
template<int MODE>
__global__ __launch_bounds__(256, 2) void gemm_nl(
    const u16* __restrict__ apk, const u16* __restrict__ bpk,
    const u16* __restrict__ bpw,
    u16* __restrict__ qb, u16* __restrict__ kb, u16* __restrict__ vtb,
    void* __restrict__ outp, const unsigned* __restrict__ flag){
  const int tid = threadIdx.x;
  const int lane = tid & 63, wid = tid >> 6;
  const int g = lane >> 4, lo = lane & 15;
  const int wm = wid >> 1, wn = wid & 1;
  const int mtb = blockIdx.x*16 + wm*8;            // 16-row tile base
  const int ntb = blockIdx.y*8  + wn*4;            // 16-col tile base

  f32x4 acc[8][4];
  const f32x4 vzero = {0.f, 0.f, 0.f, 0.f};
  #pragma unroll
  for (int mt = 0; mt < 8; ++mt)
    #pragma unroll
    for (int nt = 0; nt < 4; ++nt) acc[mt][nt] = vzero;

  const u16* ab = apk + lane*8;
  const u16* bb = bpk + lane*8;

  #define LOADF(AF, BF, kb_) do { _Pragma("unroll")                           \
    for (int mt = 0; mt < 8; ++mt)                                            \
      AF[mt] = *(const bf16x8*)(ab + (((size_t)(mtb+mt)*20 + (kb_)) << 9));   \
    _Pragma("unroll")                                                         \
    for (int nt = 0; nt < 4; ++nt)                                            \
      BF[nt] = *(const bf16x8*)(bb + (((size_t)(ntb+nt)*20 + (kb_)) << 9));   \
  } while(0)
  #define MM(AF, BF) do { _Pragma("unroll")                                   \
    for (int mt = 0; mt < 8; ++mt) _Pragma("unroll")                          \
      for (int nt = 0; nt < 4; ++nt)                                          \
        acc[mt][nt] = __builtin_amdgcn_mfma_f32_16x16x32_bf16(                \
            AF[mt], BF[nt], acc[mt][nt], 0, 0, 0);                            \
  } while(0)

  bf16x8 a0[8], b0[4], a1[8], b1[4];
  LOADF(a0, b0, 0);
  #pragma unroll 1
  for (int t = 0; t < 9; ++t){
    LOADF(a1, b1, 2*t + 1);       // prefetch next while MFMAs run
    MM(a0, b0);
    LOADF(a0, b0, 2*t + 2);
    MM(a1, b1);
  }
  LOADF(a1, b1, 19);
  MM(a0, b0);
  MM(a1, b1);
  #undef LOADF
  #undef MM

  // ---- epilogue ----
  const int ny = blockIdx.y;
  const bool f32out = (MODE == 1) && (*flag != 0u);
  const int p = ny / 5, h = ny % 5;
  #pragma unroll
  for (int mt = 0; mt < 8; ++mt)
    #pragma unroll
    for (int nt = 0; nt < 4; ++nt)
      #pragma unroll
      for (int r = 0; r < 4; ++r){
        int m  = blockIdx.x*256 + wm*128 + mt*16 + g*4 + r;
        int nn = wn*64 + nt*16 + lo;
        if (MODE == 0){
          u16 val = f2bf(acc[mt][nt][r]);
          if (p == 0)      qb[(size_t)m*640 + h*128 + nn] = val;
          else if (p == 1) kb[(size_t)m*640 + h*128 + nn] = val;
          else             vtb[((size_t)(m >> 8)*5 + h)*32768 + (size_t)nn*256 + (m & 255)] = val;
        } else {
          int col = ny*128 + nn;
          float v = acc[mt][nt][r] + bf2f(bpw[col]);
          if (f32out) ((float*)outp)[(size_t)m*640 + col] = v;
          else        ((u16*)outp)[(size_t)m*640 + col]   = f2bf(v);
        }
      }
}

// ------------------------------------------------------------------
// Attention (r9/r10 body): 512 threads / 8 waves, grid = 320.
// CHANGED: output written in PACKED A-frag order (for the no-LDS out-proj):
// elem (m,c) -> u16 [ ((m>>4)*20 + (c>>5)) <<9 ] + ((m&15)|(((c>>3)&3)<<4))*8 + (c&7)
__global__ __launch_bounds__(512, 1) void attn_fwd(const u16* __restrict__ qb,
    const u16* __restrict__ kb, const u16* __restrict__ vtb, u16* __restrict__ pko){
  __shared__ char smem[147456];
  char* k_lds  = smem;
  char* vt_lds = smem + 65536;
  char* p_lds  = smem + 131072;
  const int tid = threadIdx.x;
  const int bsh = blockIdx.x;
  const int bs = bsh / 5, h = bsh % 5;
  const u16* kbase = kb + (size_t)bs*256*640 + (size_t)h*128;
  const u16* vbase = vtb + (size_t)bsh*32768;
  #pragma unroll 4
  for (int i = 0; i < 8; ++i){
    int idx = i*512 + tid;
    int e = idx >> 4, cd = idx & 15;
    uint4 kv = *(const uint4*)(kbase + (size_t)e*640 + cd*8);
    *(uint4*)(k_lds + e*256 + ((cd ^ (e & 7)))*16) = kv;
    int d = idx >> 5, ce = idx & 31;
    uint4 vv = *(const uint4*)(vbase + d*256 + ce*8);
    *(uint4*)(vt_lds + d*512 + ((ce ^ (d & 7)))*16) = vv;
  }
  __syncthreads();
  const int lane = tid & 63, wid = tid >> 6;
  const int g = lane >> 4, lo = lane & 15;
  char* pw = p_lds + wid*2048;
  const float scale = 0.08838834764831845f;
  const f32x4 vzero = {0.f, 0.f, 0.f, 0.f};

  for (int mt2 = 0; mt2 < 2; ++mt2){
    const int crow = wid*32 + mt2*16;
    const u16* qr = qb + ((size_t)bs*256 + crow + lo)*640 + (size_t)h*128;
    bf16x8 qf[4];
    #pragma unroll
    for (int kc = 0; kc < 4; ++kc) qf[kc] = *(const bf16x8*)(qr + kc*32 + g*8);

    f32x4 acc[16];
    #pragma unroll
    for (int et = 0; et < 16; ++et) acc[et] = vzero;
    #pragma unroll
    for (int et = 0; et < 16; ++et)
      #pragma unroll
      for (int kc = 0; kc < 4; ++kc){
        bf16x8 bk = *(const bf16x8*)(k_lds + k_off(et*16 + lo, kc*32 + g*8));
        acc[et] = __builtin_amdgcn_mfma_f32_16x16x32_bf16(qf[kc], bk, acc[et], 0, 0, 0);
      }

    float mx[4] = {-3.0e38f, -3.0e38f, -3.0e38f, -3.0e38f};
    #pragma unroll
    for (int et = 0; et < 16; ++et)
      #pragma unroll
      for (int r = 0; r < 4; ++r){
        float t = acc[et][r] * scale;
        acc[et][r] = t;
        mx[r] = fmaxf(mx[r], t);
      }
    #pragma unroll
    for (int msk = 1; msk < 16; msk <<= 1)
      #pragma unroll
      for (int r = 0; r < 4; ++r) mx[r] = fmaxf(mx[r], __shfl_xor(mx[r], msk));
    float sm[4] = {0.f, 0.f, 0.f, 0.f};
    #pragma unroll
    for (int et = 0; et < 16; ++et)
      #pragma unroll
      for (int r = 0; r < 4; ++r){
        float ex = __expf(acc[et][r] - mx[r]);
        acc[et][r] = ex;
        sm[r] += ex;
      }
    #pragma unroll
    for (int msk = 1; msk < 16; msk <<= 1)
      #pragma unroll
      for (int r = 0; r < 4; ++r) sm[r] += __shfl_xor(sm[r], msk);
    float inv[4];
    #pragma unroll
    for (int r = 0; r < 4; ++r) inv[r] = 1.0f / sm[r];

    f32x4 oacc[8];
    #pragma unroll
    for (int dt = 0; dt < 8; ++dt) oacc[dt] = vzero;

    #pragma unroll
    for (int half = 0; half < 2; ++half)
      #pragma unroll
      for (int sub = 0; sub < 2; ++sub){
        #pragma unroll
        for (int et2 = 0; et2 < 4; ++et2){
          int et = half*8 + sub*4 + et2;
          #pragma unroll
          for (int r = 0; r < 4; ++r)
            *(u16*)(pw + p_off2(g*4 + r, et2*16 + lo)) = f2bf(acc[et][r] * inv[r]);
        }
        asm volatile("s_waitcnt lgkmcnt(0)" ::: "memory");
        bf16x8 pf[2];
        #pragma unroll
        for (int kc = 0; kc < 2; ++kc) pf[kc] = *(const bf16x8*)(pw + p_off2(lo, kc*32 + g*8));
        #pragma unroll
        for (int dt = 0; dt < 8; ++dt)
          #pragma unroll
          for (int kc = 0; kc < 2; ++kc){
            bf16x8 bv = *(const bf16x8*)(vt_lds + vt_off(dt*16 + lo, half*128 + sub*64 + kc*32 + g*8));
            oacc[dt] = __builtin_amdgcn_mfma_f32_16x16x32_bf16(pf[kc], bv, oacc[dt], 0, 0, 0);
          }
        asm volatile("s_waitcnt lgkmcnt(0)" ::: "memory");
      }

    // packed-order output write: m = bs*256+crow+g*4+r, c = h*128+dt*16+lo
    const int mtt = bs*16 + wid*2 + mt2;           // m >> 4
    #pragma unroll
    for (int dt = 0; dt < 8; ++dt){
      const int kbp  = h*4 + (dt >> 1);            // c >> 5
      const int sub2 = ((dt & 1) << 1) + (lo >> 3);
      u16* base = pko + (((size_t)mtt*20 + kbp) << 9) + ((sub2 << 4) << 3) + (lo & 7);
      #pragma unroll
      for (int r = 0; r < 4; ++r)
        base[(g*4 + r)*8] = f2bf(oacc[dt][r]);
    }
  }
}

// ------------------------------------------------------------------
extern "C" void kernel_launch(void* const* d_in, const int* in_sizes, int n_in,
                              void* d_out, int out_size, void* d_ws, size_t ws_size,
                              hipStream_t stream) {
  (void)in_sizes; (void)n_in; (void)out_size; (void)ws_size;
  char* ws = (char*)d_ws;
  const size_t SZ = (size_t)16384 * 640 * 2;     // 20,971,520 B
  u16* XPK  = (u16*)(ws);                         // packed x; later packed attn out
  u16* QB   = (u16*)(ws + SZ);
  u16* KB   = (u16*)(ws + 2*SZ);
  u16* VTB  = (u16*)(ws + 3*SZ);
  u16* ATP  = (u16*)(ws);                         // attn out (packed) reuses XPK
  u16* WPK  = (u16*)(ws + 4*SZ);                  // packed qkv W: 1,228,800 u16
  u16* WPPK = WPK + 1228800;                      // packed Wp:     409,600 u16
  u16* BPB  = WPPK + 409600;                      // [640]
  unsigned* FLAG = (unsigned*)(BPB + 640);

  k_convert_all<<<2961, 256, 0, stream>>>(d_in[0], d_in[1], d_in[2], d_in[3],
                                          d_in[4], d_in[5], XPK, WPK, WPPK, BPB, FLAG);

  gemm_nl<0><<<dim3(64, 15), 256, 0, stream>>>(XPK, WPK, nullptr,
                                               QB, KB, VTB, nullptr, FLAG);

  attn_fwd<<<320, 512, 0, stream>>>(QB, KB, VTB, ATP);

  gemm_nl<1><<<dim3(64, 5), 256, 0, stream>>>(ATP, WPPK, BPB,
                                              nullptr, nullptr, nullptr, d_out, FLAG);
}

// Round 16
// 150.175 us; speedup vs baseline: 1.1270x; 1.1270x over previous
//
#include <hip/hip_runtime.h>

// B=2, S=32, C=256, L=640, H=5, D=128.  M = B*S*C = 16384, L = 640 = H*D.
// Best-of-breed composition: r7 convert (x-skip) + r3 gemm_core (72.2us
// measured) for both GEMMs + r9 merged 512-thr attn.
//
// ws layout (bytes):
//   XB   @ 0    : x bf16 [16384][640] (written only when input is fp32)
//                 -- reused as attn_out (AT) after attn
//   QB   @ SZ   : q bf16 [16384][640] (col = h*128+d)
//   KB   @ 2SZ  : k bf16 [16384][640]
//   VTB  @ 3SZ  : v transposed bf16 [320 bsh][128 d][256 e]
//   WSTK @ 4SZ  : Wq|Wk|Wv stacked bf16 [1920][640]
//   WPB         : Wp bf16 [640][640];  BPB: bp bf16 [640];  FLAG: u32

typedef unsigned short u16;
typedef __bf16 bf16x8 __attribute__((ext_vector_type(8)));
typedef float f32x4 __attribute__((ext_vector_type(4)));

__device__ __forceinline__ u16 f2bf(float f){
  union { float f; unsigned u; } v; v.f = f;
  unsigned r = v.u + 0x7fffu + ((v.u >> 16) & 1u);
  return (u16)(r >> 16);
}
__device__ __forceinline__ float bf2f(u16 u){
  union { unsigned u; float f; } v; v.u = ((unsigned)u) << 16;
  return v.f;
}

__device__ __forceinline__ void gload16(const u16* g, char* l){
  __builtin_amdgcn_global_load_lds((const __attribute__((address_space(1))) void*)g,
                                   (__attribute__((address_space(3))) void*)l, 16, 0, 0);
}

// ---- attention LDS swizzles (verified r1-r15) ----
__device__ __forceinline__ int k_off (int e, int d){ return e*256 + (((d>>3) ^ (e&7)))*16 + (d&7)*2; }
__device__ __forceinline__ int vt_off(int d, int e){ return d*512 + (((e>>3) ^ (d&7)))*16 + (e&7)*2; }
__device__ __forceinline__ int p_off2(int c, int el){ return c*128 + (((el>>3) ^ (c&7)))*16 + (el&7)*2; }

// ------------------------------------------------------------------
// Fused dtype-detect + convert (r7 verbatim): skip x copy when already bf16.
// word4 segments: x [0,2621440) | wstk 307200 | wp 102400 | bp 160.
__global__ __launch_bounds__(256) void k_convert_all(
    const void* __restrict__ xsrc, const void* __restrict__ s1, const void* __restrict__ s2,
    const void* __restrict__ s3, const void* __restrict__ s4, const void* __restrict__ s5,
    u16* __restrict__ xb, u16* __restrict__ wstk, u16* __restrict__ wpb,
    u16* __restrict__ bpb, unsigned* __restrict__ flagOut){
  __shared__ unsigned sflag;
  const int tid = threadIdx.x;
  const u16* xs = (const u16*)xsrc;
  if (tid < 64){
    int cnt = 0;
    for (int i = tid; i < 1024; i += 64){
      unsigned e = (xs[2*i] >> 7) & 0xffu;
      cnt += (e >= 143u) ? 1 : 0;
    }
    #pragma unroll
    for (int m = 1; m < 64; m <<= 1) cnt += __shfl_xor(cnt, m);
    if (tid == 0) sflag = (cnt > 16) ? 1u : 0u;
  }
  __syncthreads();
  const unsigned flag = sflag;
  if (blockIdx.x == 0 && tid == 0) *flagOut = flag;
  if (blockIdx.x < 2560 && flag == 0u) return;     // x stays in d_in[0]

  #pragma unroll
  for (int it = 0; it < 4; ++it){
    size_t i = (size_t)blockIdx.x*1024 + it*256 + tid;
    if (i >= 3031200) break;
    const void* src; size_t off; u16* dp;
    if (i < 2621440){ src = xsrc; off = i; dp = xb + i*4; }
    else {
      size_t j = i - 2621440;
      if (j < 307200){
        int seg = (int)(j / 102400);
        off = j - (size_t)seg*102400;
        src = (seg==0) ? s1 : (seg==1) ? s2 : s3;
        dp = wstk + j*4;
      } else if (j < 409600){
        off = j - 307200; src = s4; dp = wpb + off*4;
      } else { off = j - 409600; src = s5; dp = bpb + off*4; }
    }
    if (flag){
      float4 v = ((const float4*)src)[off];
      ushort4 o;
      o.x = f2bf(v.x); o.y = f2bf(v.y); o.z = f2bf(v.z); o.w = f2bf(v.w);
      *(ushort4*)dp = o;
    } else {
      *(ushort4*)dp = ((const ushort4*)src)[off];
    }
  }
}

// ------------------------------------------------------------------
// r3 gemm_core VERBATIM (measured 72.2us for qkv): 128x128 tile, K=640,
// BK=64, double-buffered 2x32KB LDS, both operands via global_load_lds
// with pre-swizzled source + XOR'd reads (0 measured bank conflicts),
// stage(next)-before-compute(cur), one __syncthreads per half-step.
__device__ __forceinline__ void gemm_core(const u16* __restrict__ Ag, const u16* __restrict__ Bg,
                                          char* lds, f32x4 acc[4][4]){
  const int tid = threadIdx.x;
  const int lane = tid & 63, wid = tid >> 6;
  const int g = lane >> 4, lo = lane & 15;
  const int wm = wid >> 1, wn = wid & 1;
  const f32x4 vzero = {0.f, 0.f, 0.f, 0.f};
  #pragma unroll
  for (int mt = 0; mt < 4; ++mt)
    #pragma unroll
    for (int nt = 0; nt < 4; ++nt) acc[mt][nt] = vzero;

  const int srow = lane >> 3;
  const size_t soff = (size_t)srow*640 + (size_t)(((lane & 7) ^ srow) * 8);

  #define STAGE(buf, kt) do {                                            \
    const u16* Akt_ = Ag + (kt)*64;                                      \
    const u16* Bkt_ = Bg + (kt)*64;                                      \
    _Pragma("unroll")                                                    \
    for (int cc = 0; cc < 4; ++cc){                                      \
      int c_ = wid*4 + cc;                                               \
      gload16(Akt_ + (size_t)c_*8*640 + soff, (buf) + c_*1024);          \
      gload16(Bkt_ + (size_t)c_*8*640 + soff, (buf) + 16384 + c_*1024);  \
    }                                                                    \
  } while(0)

  #define COMPUTE(buf) do {                                              \
    bf16x8 af[4][2], bfr[4][2];                                          \
    _Pragma("unroll")                                                    \
    for (int mt = 0; mt < 4; ++mt){                                      \
      int rr = wm*64 + mt*16 + lo;                                       \
      _Pragma("unroll")                                                  \
      for (int ks = 0; ks < 2; ++ks)                                     \
        af[mt][ks] = *(const bf16x8*)((buf) + rr*128 + (((ks*4+g) ^ (lo&7))*16)); \
    }                                                                    \
    _Pragma("unroll")                                                    \
    for (int nt = 0; nt < 4; ++nt){                                      \
      int rr = wn*64 + nt*16 + lo;                                       \
      _Pragma("unroll")                                                  \
      for (int ks = 0; ks < 2; ++ks)                                     \
        bfr[nt][ks] = *(const bf16x8*)((buf) + 16384 + rr*128 + (((ks*4+g) ^ (lo&7))*16)); \
    }                                                                    \
    _Pragma("unroll")                                                    \
    for (int mt = 0; mt < 4; ++mt)                                       \
      _Pragma("unroll")                                                  \
      for (int nt = 0; nt < 4; ++nt)                                     \
        _Pragma("unroll")                                                \
        for (int ks = 0; ks < 2; ++ks)                                   \
          acc[mt][nt] = __builtin_amdgcn_mfma_f32_16x16x32_bf16(af[mt][ks], bfr[nt][ks], acc[mt][nt], 0, 0, 0); \
  } while(0)

  char* buf0 = lds;
  char* buf1 = lds + 32768;

  STAGE(buf0, 0);
  __syncthreads();
  #pragma unroll 1
  for (int kt2 = 0; kt2 < 5; ++kt2){
    int kt = kt2*2;
    STAGE(buf1, kt+1);          // issue next-tile loads first (latency hidden)
    COMPUTE(buf0);
    __syncthreads();            // drains vmcnt -> buf1 ready
    if (kt2 < 4) STAGE(buf0, kt+2);
    COMPUTE(buf1);
    __syncthreads();
  }
  #undef STAGE
  #undef COMPUTE
}

// QKV projection (r3 epilogue): grid (128 mtiles, 15), by -> p=by/5, h=by%5.
// A = x direct from d_in[0] when bf16, else converted XB.
__global__ __launch_bounds__(256, 2) void gemm_qkv(const u16* __restrict__ xraw,
    const u16* __restrict__ xb, const unsigned* __restrict__ flag,
    const u16* __restrict__ wstk,
    u16* __restrict__ qb, u16* __restrict__ kb, u16* __restrict__ vtb){
  __shared__ char smem[65536];
  const int m0 = blockIdx.x * 128;
  const int by = blockIdx.y;
  const u16* Ag = (*flag != 0u) ? xb : xraw;
  f32x4 acc[4][4];
  gemm_core(Ag + (size_t)m0*640, wstk + (size_t)by*128*640, smem, acc);
  const int tid = threadIdx.x, lane = tid & 63, wid = tid >> 6;
  const int g = lane >> 4, lo = lane & 15;
  const int wm = wid >> 1, wn = wid & 1;
  const int p = by / 5, h = by % 5;
  #pragma unroll
  for (int mt = 0; mt < 4; ++mt)
    #pragma unroll
    for (int nt = 0; nt < 4; ++nt)
      #pragma unroll
      for (int r = 0; r < 4; ++r){
        int m  = m0 + wm*64 + mt*16 + g*4 + r;       // global row (b,s,c)
        int nn = wn*64 + nt*16 + lo;                 // d within head, 0..127
        u16 val = f2bf(acc[mt][nt][r]);
        if (p == 0)      qb[(size_t)m*640 + h*128 + nn] = val;
        else if (p == 1) kb[(size_t)m*640 + h*128 + nn] = val;
        else             vtb[((size_t)(m >> 8)*5 + h)*32768 + (size_t)nn*256 + (m & 255)] = val;
      }
}

// Output projection + bias (r3 verbatim).
__global__ __launch_bounds__(256, 2) void gemm_out(const u16* __restrict__ at,
    const u16* __restrict__ wpw, const u16* __restrict__ bpw,
    void* __restrict__ out, const unsigned* __restrict__ flag){
  __shared__ char smem[65536];
  const int m0 = blockIdx.x * 128;
  const int n0 = blockIdx.y * 128;
  f32x4 acc[4][4];
  gemm_core(at + (size_t)m0*640, wpw + (size_t)n0*640, smem, acc);
  const int tid = threadIdx.x, lane = tid & 63, wid = tid >> 6;
  const int g = lane >> 4, lo = lane & 15;
  const int wm = wid >> 1, wn = wid & 1;
  const bool f32out = (*flag != 0u);
  #pragma unroll
  for (int mt = 0; mt < 4; ++mt)
    #pragma unroll
    for (int nt = 0; nt < 4; ++nt){
      int col = n0 + wn*64 + nt*16 + lo;
      float bv = bf2f(bpw[col]);
      #pragma unroll
      for (int r = 0; r < 4; ++r){
        int m = m0 + wm*64 + mt*16 + g*4 + r;
        float v = acc[mt][nt][r] + bv;
        if (f32out) ((float*)out)[(size_t)m*640 + col] = v;
        else        ((u16*)out)[(size_t)m*640 + col]   = f2bf(v);
      }
    }
}

// ------------------------------------------------------------------
// Attention (r9/r10 verbatim, best measured ~37us): 512 thr / 8 waves,
// grid = 320 (one block per b,s,h); k+vT staged once; rowmajor output.
__global__ __launch_bounds__(512, 1) void attn_fwd(const u16* __restrict__ qb,
    const u16* __restrict__ kb, const u16* __restrict__ vtb, u16* __restrict__ ob){
  __shared__ char smem[147456];
  char* k_lds  = smem;
  char* vt_lds = smem + 65536;
  char* p_lds  = smem + 131072;
  const int tid = threadIdx.x;
  const int bsh = blockIdx.x;
  const int bs = bsh / 5, h = bsh % 5;
  const u16* kbase = kb + (size_t)bs*256*640 + (size_t)h*128;
  const u16* vbase = vtb + (size_t)bsh*32768;
  #pragma unroll 4
  for (int i = 0; i < 8; ++i){
    int idx = i*512 + tid;
    int e = idx >> 4, cd = idx & 15;
    uint4 kv = *(const uint4*)(kbase + (size_t)e*640 + cd*8);
    *(uint4*)(k_lds + e*256 + ((cd ^ (e & 7)))*16) = kv;
    int d = idx >> 5, ce = idx & 31;
    uint4 vv = *(const uint4*)(vbase + d*256 + ce*8);
    *(uint4*)(vt_lds + d*512 + ((ce ^ (d & 7)))*16) = vv;
  }
  __syncthreads();
  const int lane = tid & 63, wid = tid >> 6;
  const int g = lane >> 4, lo = lane & 15;
  char* pw = p_lds + wid*2048;
  const float scale = 0.08838834764831845f;
  const f32x4 vzero = {0.f, 0.f, 0.f, 0.f};

  for (int mt = 0; mt < 2; ++mt){
    const int crow = wid*32 + mt*16;
    const u16* qr = qb + ((size_t)bs*256 + crow + lo)*640 + (size_t)h*128;
    bf16x8 qf[4];
    #pragma unroll
    for (int kc = 0; kc < 4; ++kc) qf[kc] = *(const bf16x8*)(qr + kc*32 + g*8);

    f32x4 acc[16];
    #pragma unroll
    for (int et = 0; et < 16; ++et) acc[et] = vzero;
    #pragma unroll
    for (int et = 0; et < 16; ++et)
      #pragma unroll
      for (int kc = 0; kc < 4; ++kc){
        bf16x8 bk = *(const bf16x8*)(k_lds + k_off(et*16 + lo, kc*32 + g*8));
        acc[et] = __builtin_amdgcn_mfma_f32_16x16x32_bf16(qf[kc], bk, acc[et], 0, 0, 0);
      }

    float mx[4] = {-3.0e38f, -3.0e38f, -3.0e38f, -3.0e38f};
    #pragma unroll
    for (int et = 0; et < 16; ++et)
      #pragma unroll
      for (int r = 0; r < 4; ++r){
        float t = acc[et][r] * scale;
        acc[et][r] = t;
        mx[r] = fmaxf(mx[r], t);
      }
    #pragma unroll
    for (int msk = 1; msk < 16; msk <<= 1)
      #pragma unroll
      for (int r = 0; r < 4; ++r) mx[r] = fmaxf(mx[r], __shfl_xor(mx[r], msk));
    float sm[4] = {0.f, 0.f, 0.f, 0.f};
    #pragma unroll
    for (int et = 0; et < 16; ++et)
      #pragma unroll
      for (int r = 0; r < 4; ++r){
        float ex = __expf(acc[et][r] - mx[r]);
        acc[et][r] = ex;
        sm[r] += ex;
      }
    #pragma unroll
    for (int msk = 1; msk < 16; msk <<= 1)
      #pragma unroll
      for (int r = 0; r < 4; ++r) sm[r] += __shfl_xor(sm[r], msk);
    float inv[4];
    #pragma unroll
    for (int r = 0; r < 4; ++r) inv[r] = 1.0f / sm[r];

    f32x4 oacc[8];
    #pragma unroll
    for (int dt = 0; dt < 8; ++dt) oacc[dt] = vzero;

    #pragma unroll
    for (int half = 0; half < 2; ++half)
      #pragma unroll
      for (int sub = 0; sub < 2; ++sub){
        #pragma unroll
        for (int et2 = 0; et2 < 4; ++et2){
          int et = half*8 + sub*4 + et2;
          #pragma unroll
          for (int r = 0; r < 4; ++r)
            *(u16*)(pw + p_off2(g*4 + r, et2*16 + lo)) = f2bf(acc[et][r] * inv[r]);
        }
        asm volatile("s_waitcnt lgkmcnt(0)" ::: "memory");
        bf16x8 pf[2];
        #pragma unroll
        for (int kc = 0; kc < 2; ++kc) pf[kc] = *(const bf16x8*)(pw + p_off2(lo, kc*32 + g*8));
        #pragma unroll
        for (int dt = 0; dt < 8; ++dt)
          #pragma unroll
          for (int kc = 0; kc < 2; ++kc){
            bf16x8 bv = *(const bf16x8*)(vt_lds + vt_off(dt*16 + lo, half*128 + sub*64 + kc*32 + g*8));
            oacc[dt] = __builtin_amdgcn_mfma_f32_16x16x32_bf16(pf[kc], bv, oacc[dt], 0, 0, 0);
          }
        asm volatile("s_waitcnt lgkmcnt(0)" ::: "memory");
      }

    u16* orow = ob + ((size_t)bs*256 + crow)*640 + (size_t)h*128;
    #pragma unroll
    for (int dt = 0; dt < 8; ++dt)
      #pragma unroll
      for (int r = 0; r < 4; ++r)
        orow[(size_t)(g*4 + r)*640 + dt*16 + lo] = f2bf(oacc[dt][r]);
  }
}

// ------------------------------------------------------------------
extern "C" void kernel_launch(void* const* d_in, const int* in_sizes, int n_in,
                              void* d_out, int out_size, void* d_ws, size_t ws_size,
                              hipStream_t stream) {
  (void)in_sizes; (void)n_in; (void)out_size; (void)ws_size;
  char* ws = (char*)d_ws;
  const size_t SZ = (size_t)16384 * 640 * 2;     // 20,971,520 B
  u16* XB   = (u16*)(ws);
  u16* QB   = (u16*)(ws + SZ);
  u16* KB   = (u16*)(ws + 2*SZ);
  u16* VTB  = (u16*)(ws + 3*SZ);
  u16* AT   = XB;                                 // attn output reuses XB
  u16* WSTK = (u16*)(ws + 4*SZ);                  // [1920][640]
  u16* WPB  = WSTK + 1228800;                     // [640][640]
  u16* BPB  = WPB + 409600;                       // [640]
  unsigned* FLAG = (unsigned*)(BPB + 640);

  k_convert_all<<<2961, 256, 0, stream>>>(d_in[0], d_in[1], d_in[2], d_in[3],
                                          d_in[4], d_in[5], XB, WSTK, WPB, BPB, FLAG);

  gemm_qkv<<<dim3(128, 15), 256, 0, stream>>>((const u16*)d_in[0], XB, FLAG,
                                              WSTK, QB, KB, VTB);
  attn_fwd<<<320, 512, 0, stream>>>(QB, KB, VTB, AT);
  gemm_out<<<dim3(128, 5), 256, 0, stream>>>(AT, WPB, BPB, d_out, FLAG);
}